// Round 6
// baseline (77.839 us; speedup 1.0000x reference)
//
#include <hip/hip_runtime.h>

#define NN 1024
#define DD 128
#define REP_MAIN 8
#define REP_RED 64

typedef float f32x4 __attribute__((ext_vector_type(4)));
typedef _Float16 f16x4 __attribute__((ext_vector_type(4)));
typedef _Float16 f16x8 __attribute__((ext_vector_type(8)));

__device__ __forceinline__ f16x8 cvt8(f32x4 a, f32x4 b) {
  f16x8 r;
  r[0] = (_Float16)a.x; r[1] = (_Float16)a.y; r[2] = (_Float16)a.z; r[3] = (_Float16)a.w;
  r[4] = (_Float16)b.x; r[5] = (_Float16)b.y; r[6] = (_Float16)b.z; r[7] = (_Float16)b.w;
  return r;
}

// ws layout (f32 units):
//   [0 .. 8192)            S_part[js][i]   (8 x 1024)
//   [8192 .. 8192+1048576) part[js][i][d]  (8 x 1024 x 128) unscaled K'@Y
#define WS_PART 8192

// DIAGNOSTIC build: identical structure to round 4 (best known, 17.4us), with
// the body repeated REP_MAIN times (memory-clobbered each iter so loads
// re-issue) to lift this kernel above the 40us harness fills in the rocprof
// top-5 and expose its counters. Output is idempotent across reps.
__global__ __launch_bounds__(256, 2) void gk_main(const float* __restrict__ X,
                                                  const float* __restrict__ Y,
                                                  const int* __restrict__ hp,
                                                  float* __restrict__ out,
                                                  float* __restrict__ ws) {
  __shared__ __align__(16) _Float16 Ks[16][136];   // K' f16 scaled
  __shared__ float yys[128];
  __shared__ unsigned msc[16];
  __shared__ float Sred[16];

  const int tid  = threadIdx.x;
  const int js   = blockIdx.x;          // 0..7   (j block of 128)
  const int ib   = blockIdx.y;          // 0..63  (i block of 16)
  const int lane = tid & 63;
  const int w    = tid >> 6;            // wave 0..3
  const int g    = lane >> 4;           // k-group 0..3
  const int li   = lane & 15;

  const float fh = (float)hp[0];
  const float inv_h2 = 1.0f / (fh * fh);

  for (int rep = 0; rep < REP_MAIN; ++rep) {
    asm volatile("" ::: "memory");   // force re-issue of all loads each rep
    __syncthreads();                 // prev-iter epilogue reads done before re-init
    if (tid < 16) { msc[tid] = 0u; Sred[tid] = 0.0f; }

    // ---- issue ALL independent global loads up front ----
    const float* Xr = X + (size_t)(ib * 16 + li) * DD;
    f32x4 xa[4][2];
    #pragma unroll
    for (int kt = 0; kt < 4; ++kt) {
      int d0 = kt * 32 + g * 8;
      xa[kt][0] = *(const f32x4*)(Xr + d0);
      xa[kt][1] = *(const f32x4*)(Xr + d0 + 4);
    }
    // phase-D B-operand prefetch: Y columns, lane=d
    const int dA = w * 32 + li;
    const int dB = dA + 16;
    float bpre0[4][8], bpre1[4][8];
    #pragma unroll
    for (int kt = 0; kt < 4; ++kt) {
      const float* Yb = Y + (size_t)(js * 128 + kt * 32 + g * 8) * DD;
      #pragma unroll
      for (int e = 0; e < 8; ++e) {
        bpre0[kt][e] = Yb[e * DD + dA];
        bpre1[kt][e] = Yb[e * DD + dB];
      }
    }

    float xx = 0.f;
    #pragma unroll
    for (int kt = 0; kt < 4; ++kt)
      #pragma unroll
      for (int c = 0; c < 4; ++c)
        xx += xa[kt][0][c] * xa[kt][0][c] + xa[kt][1][c] * xa[kt][1][c];
    xx += __shfl_xor(xx, 16); xx += __shfl_xor(xx, 32);

    // ---- Phase A: QK^T from global f32 Y rows; norms in-register ----
    const float* Yr0 = Y + (size_t)(js * 128 + w * 32 + li) * DD;
    const float* Yr1 = Yr0 + 16 * DD;
    f32x4 acc0 = {0.f, 0.f, 0.f, 0.f}, acc1 = {0.f, 0.f, 0.f, 0.f};
    float yy0 = 0.f, yy1 = 0.f;
    #pragma unroll
    for (int kt = 0; kt < 4; ++kt) {
      int d0 = kt * 32 + g * 8;
      f32x4 a0 = *(const f32x4*)(Yr0 + d0), b0 = *(const f32x4*)(Yr0 + d0 + 4);
      f32x4 a1 = *(const f32x4*)(Yr1 + d0), b1 = *(const f32x4*)(Yr1 + d0 + 4);
      #pragma unroll
      for (int c = 0; c < 4; ++c) {
        yy0 += a0[c] * a0[c] + b0[c] * b0[c];
        yy1 += a1[c] * a1[c] + b1[c] * b1[c];
      }
      f16x8 bf = cvt8(xa[kt][0], xa[kt][1]);
      acc0 = __builtin_amdgcn_mfma_f32_16x16x32_f16(cvt8(a0, b0), bf, acc0, 0, 0, 0);
      acc1 = __builtin_amdgcn_mfma_f32_16x16x32_f16(cvt8(a1, b1), bf, acc1, 0, 0, 0);
    }
    yy0 += __shfl_xor(yy0, 16); yy0 += __shfl_xor(yy0, 32);
    yy1 += __shfl_xor(yy1, 16); yy1 += __shfl_xor(yy1, 32);
    if (lane < 16) { yys[w * 32 + lane] = yy0; yys[w * 32 + 16 + lane] = yy1; }
    __syncthreads();   // b1: yys ready, msc/Sred init visible

    // ---- exp ----
    float K[8];
    float m = 0.f, sp = 0.f;
    #pragma unroll
    for (int t = 0; t < 2; ++t) {
      f32x4 a = t ? acc1 : acc0;
      #pragma unroll
      for (int r = 0; r < 4; ++r) {
        int jl = w * 32 + t * 16 + 4 * g + r;
        float e = fminf((a[r] - 0.5f * (xx + yys[jl])) * inv_h2, 0.0f);
        float kv = exp2f(e * 1.44269504088896341f);
        K[t * 4 + r] = kv; m = fmaxf(m, kv); sp += kv;
      }
    }
    {
      float* kb = out + (size_t)(ib * 16 + li) * NN + js * 128 + w * 32 + 4 * g;
      f32x4 k0 = { K[0], K[1], K[2], K[3] };
      f32x4 k1 = { K[4], K[5], K[6], K[7] };
      *(f32x4*)kb = k0;
      *(f32x4*)(kb + 16) = k1;
    }
    m = fmaxf(m, __shfl_xor(m, 16)); m = fmaxf(m, __shfl_xor(m, 32));
    sp += __shfl_xor(sp, 16);        sp += __shfl_xor(sp, 32);
    if (lane < 16) {
      atomicMax(&msc[li], __float_as_uint(m));
      atomicAdd(&Sred[li], sp);
    }
    __syncthreads();   // b2: msc, Sred complete

    // ---- scaled K' (f16) ----
    {
      unsigned ue = (msc[li] >> 23) & 0xffu;
      unsigned se = 266u - ue; if (se > 254u) se = 254u;
      float scale = __uint_as_float(se << 23);
      #pragma unroll
      for (int t = 0; t < 2; ++t) {
        f16x4 q;
        #pragma unroll
        for (int r = 0; r < 4; ++r) q[r] = (_Float16)(K[t * 4 + r] * scale);
        *(f16x4*)&Ks[li][w * 32 + t * 16 + 4 * g] = q;
      }
    }
    __syncthreads();   // b3: Ks ready

    // ---- Phase D: K' @ Y from prefetched registers ----
    f32x4 c0 = {0.f, 0.f, 0.f, 0.f}, c1 = {0.f, 0.f, 0.f, 0.f};
    #pragma unroll
    for (int kt = 0; kt < 4; ++kt) {
      f16x8 af = *(const f16x8*)&Ks[li][kt * 32 + g * 8];
      f16x8 b0, b1;
      #pragma unroll
      for (int e = 0; e < 8; ++e) {
        b0[e] = (_Float16)bpre0[kt][e];
        b1[e] = (_Float16)bpre1[kt][e];
      }
      c0 = __builtin_amdgcn_mfma_f32_16x16x32_f16(af, b0, c0, 0, 0, 0);
      c1 = __builtin_amdgcn_mfma_f32_16x16x32_f16(af, b1, c1, 0, 0, 0);
    }

    // ---- epilogue: unscale, store private partial slab ----
    float* pb = ws + WS_PART + (size_t)js * (NN * DD) + (size_t)(ib * 16) * DD;
    #pragma unroll
    for (int r = 0; r < 4; ++r) {
      int il = 4 * g + r;
      unsigned ue2 = (msc[il] >> 23) & 0xffu;
      unsigned se2 = 266u - ue2; if (se2 > 254u) se2 = 254u;
      float invs = __uint_as_float((254u - se2) << 23);
      pb[il * DD + dA] = c0[r] * invs;
      pb[il * DD + dB] = c1[r] * invs;
    }
    if (tid < 16) ws[js * NN + ib * 16 + tid] = Sred[tid];
  }
}

// dK[i][d] = inv_h2 * (sum_js part[js][i][d] - (sum_js S[js][i]) * X[i][d])
// DIAGNOSTIC: repeated REP_RED times (memory-clobbered) for counter visibility.
__global__ __launch_bounds__(256) void dk_reduce(const float* __restrict__ X,
                                                 const int* __restrict__ hp,
                                                 const float* __restrict__ ws,
                                                 float* __restrict__ out) {
  const int unit = blockIdx.x * 256 + threadIdx.x;   // 0..32767 (f32x4 units)
  const int i  = unit >> 5;
  const int d0 = (unit & 31) * 4;
  const float fh = (float)hp[0];
  const float inv_h2 = 1.0f / (fh * fh);

  for (int rep = 0; rep < REP_RED; ++rep) {
    asm volatile("" ::: "memory");
    f32x4 acc = {0.f, 0.f, 0.f, 0.f};
    float s = 0.f;
    #pragma unroll
    for (int js = 0; js < 8; ++js) {
      f32x4 p = *(const f32x4*)(ws + WS_PART + (size_t)js * (NN * DD) + (size_t)i * DD + d0);
      acc.x += p.x; acc.y += p.y; acc.z += p.z; acc.w += p.w;
      s += ws[js * NN + i];
    }
    f32x4 xv = *(const f32x4*)(X + (size_t)i * DD + d0);
    f32x4 r;
    r.x = (acc.x - s * xv.x) * inv_h2;
    r.y = (acc.y - s * xv.y) * inv_h2;
    r.z = (acc.z - s * xv.z) * inv_h2;
    r.w = (acc.w - s * xv.w) * inv_h2;
    *(f32x4*)(out + (size_t)NN * NN + (size_t)i * DD + d0) = r;
  }
}

extern "C" void kernel_launch(void* const* d_in, const int* in_sizes, int n_in,
                              void* d_out, int out_size, void* d_ws, size_t ws_size,
                              hipStream_t stream) {
  const float* X  = (const float*)d_in[0];
  const float* Y  = (const float*)d_in[1];
  const int*   hp = (const int*)d_in[2];
  float* out = (float*)d_out;
  float* ws  = (float*)d_ws;    // needs (8192 + 1048576) f32 ≈ 4.2 MB

  hipLaunchKernelGGL(gk_main, dim3(8, 64), dim3(256), 0, stream, X, Y, hp, out, ws);
  hipLaunchKernelGGL(dk_reduce, dim3(128), dim3(256), 0, stream, X, hp, ws, out);
}

// Round 7
// 18.926 us; speedup vs baseline: 4.1129x; 4.1129x over previous
//
#include <hip/hip_runtime.h>

#define NN 1024
#define DD 128

typedef float f32x4 __attribute__((ext_vector_type(4)));
typedef _Float16 f16x8 __attribute__((ext_vector_type(8)));

union H2 { unsigned u; _Float16 h[2]; };

__device__ __forceinline__ f16x8 cvt8(f32x4 a, f32x4 b) {
  f16x8 r;
  r[0] = (_Float16)a.x; r[1] = (_Float16)a.y; r[2] = (_Float16)a.z; r[3] = (_Float16)a.w;
  r[4] = (_Float16)b.x; r[5] = (_Float16)b.y; r[6] = (_Float16)b.z; r[7] = (_Float16)b.w;
  return r;
}

// ws layout (f32 units):
//   [0 .. 32768)               S_part[js*4+w][i]  (32 x 1024)
//   [32768 .. 32768+1048576)   part[js][i][d]     (8 x 1024 x 128)
#define WS_S 32768

// Grid (8 js, 64 ib), 256 thr = 4 waves. Wave w owns j-window js*128+w*32..+32
// and runs the ENTIRE pipeline autonomously (no barrier until the final
// cross-wave dK reduce): QK^T (swapped, lane=i), per-wave norms/max/sum via
// shfl, per-wave dynamic f16 scale, K' @ Y with A-frag from a wave-private
// H2-packed LDS Y tile (1 ds_read_b128) and B-frag = own K' registers.
__global__ __launch_bounds__(256, 2) void gk_main(const float* __restrict__ X,
                                                  const float* __restrict__ Y,
                                                  const int* __restrict__ hp,
                                                  float* __restrict__ out,
                                                  float* __restrict__ ws) {
  __shared__ __align__(16) char smem[4][8192];   // per-wave: Ytp (f16 pairs) then dkpart (f32)

  const int tid  = threadIdx.x;
  const int js   = blockIdx.x;          // 0..7
  const int ib   = blockIdx.y;          // 0..63
  const int lane = tid & 63;
  const int w    = tid >> 6;            // wave 0..3
  const int g    = lane >> 4;           // k-group 0..3
  const int li   = lane & 15;

  const float fh = (float)hp[0];
  const float inv_h2 = 1.0f / (fh * fh);

  unsigned* ytp = (unsigned*)smem[w];   // [d 0..127][pair 0..15]  (pair p = rows p, p+16)
  float*    dkw = (float*)smem[w];      // [i 0..15][d 0..127]  (aliased, written after reads)

  // ---- X fragments + |x|^2 ----
  const float* Xr = X + (size_t)(ib * 16 + li) * DD;
  f32x4 xa[4][2];
  float xx = 0.f;
  #pragma unroll
  for (int kt = 0; kt < 4; ++kt) {
    int d0 = kt * 32 + g * 8;
    xa[kt][0] = *(const f32x4*)(Xr + d0);
    xa[kt][1] = *(const f32x4*)(Xr + d0 + 4);
    #pragma unroll
    for (int c = 0; c < 4; ++c)
      xx += xa[kt][0][c] * xa[kt][0][c] + xa[kt][1][c] * xa[kt][1][c];
  }
  xx += __shfl_xor(xx, 16); xx += __shfl_xor(xx, 32);

  // ---- Y rows (own window): yy, QK^T MFMAs, and H2-packed LDS Y tile ----
  const float* Yr0 = Y + (size_t)(js * 128 + w * 32 + li) * DD;
  const float* Yr1 = Yr0 + 16 * DD;
  f32x4 acc0 = {0.f, 0.f, 0.f, 0.f}, acc1 = {0.f, 0.f, 0.f, 0.f};
  float yy0 = 0.f, yy1 = 0.f;
  #pragma unroll
  for (int kt = 0; kt < 4; ++kt) {
    int d0 = kt * 32 + g * 8;
    f32x4 a0 = *(const f32x4*)(Yr0 + d0), a1 = *(const f32x4*)(Yr0 + d0 + 4);
    f32x4 b0 = *(const f32x4*)(Yr1 + d0), b1 = *(const f32x4*)(Yr1 + d0 + 4);
    #pragma unroll
    for (int c = 0; c < 4; ++c) {
      yy0 += a0[c] * a0[c] + a1[c] * a1[c];
      yy1 += b0[c] * b0[c] + b1[c] * b1[c];
    }
    f16x8 af0 = cvt8(a0, a1);            // row li
    f16x8 af1 = cvt8(b0, b1);            // row li+16
    #pragma unroll
    for (int c = 0; c < 8; ++c) {        // pack (row li, row li+16) pairs at pair-idx li
      H2 pk; pk.h[0] = af0[c]; pk.h[1] = af1[c];
      ytp[(d0 + c) * 16 + li] = pk.u;
    }
    f16x8 bf = cvt8(xa[kt][0], xa[kt][1]);
    acc0 = __builtin_amdgcn_mfma_f32_16x16x32_f16(af0, bf, acc0, 0, 0, 0);
    acc1 = __builtin_amdgcn_mfma_f32_16x16x32_f16(af1, bf, acc1, 0, 0, 0);
  }
  yy0 += __shfl_xor(yy0, 16); yy0 += __shfl_xor(yy0, 32);
  yy1 += __shfl_xor(yy1, 16); yy1 += __shfl_xor(yy1, 32);

  // gather the 4 row-norms this thread's output rows need (wave-local shfl)
  float y0r[4], y1r[4];
  #pragma unroll
  for (int r = 0; r < 4; ++r) {
    y0r[r] = __shfl(yy0, 4 * g + r);
    y1r[r] = __shfl(yy1, 4 * g + r);
  }

  // ---- exp: K = exp(inv_h2*(xy - 0.5(xx+yy))), clamped <= 1 ----
  float K0[4], K1[4];
  float m = 0.f, sp = 0.f;
  #pragma unroll
  for (int r = 0; r < 4; ++r) {
    float e0 = fminf((acc0[r] - 0.5f * (xx + y0r[r])) * inv_h2, 0.0f);
    float e1 = fminf((acc1[r] - 0.5f * (xx + y1r[r])) * inv_h2, 0.0f);
    K0[r] = exp2f(e0 * 1.44269504088896341f);
    K1[r] = exp2f(e1 * 1.44269504088896341f);
    m = fmaxf(m, fmaxf(K0[r], K1[r]));
    sp += K0[r] + K1[r];
  }
  // K store: rows=li, cols 4g..+3 and 16+4g..+3 (16 full 64B lines / instr)
  {
    float* kb = out + (size_t)(ib * 16 + li) * NN + js * 128 + w * 32;
    f32x4 k0 = { K0[0], K0[1], K0[2], K0[3] };
    f32x4 k1 = { K1[0], K1[1], K1[2], K1[3] };
    *(f32x4*)(kb + 4 * g) = k0;
    *(f32x4*)(kb + 16 + 4 * g) = k1;
  }
  // per-(wave,i-row) stats via shfl only
  m  = fmaxf(m, __shfl_xor(m, 16));  m  = fmaxf(m, __shfl_xor(m, 32));
  sp += __shfl_xor(sp, 16);          sp += __shfl_xor(sp, 32);
  if (lane < 16) ws[(size_t)(js * 4 + w) * NN + ib * 16 + lane] = sp;

  unsigned ue = (__float_as_uint(m) >> 23) & 0xffu;
  unsigned se = 266u - ue; if (se > 254u) se = 254u;    // K'max in [2^12,2^13)
  float scale = __uint_as_float(se << 23);
  float invs  = __uint_as_float((254u - se) << 23);

  // B-frag = own K' regs, interleaved to match the H2 pair order (j, j+16)
  f16x8 bq;
  #pragma unroll
  for (int r = 0; r < 4; ++r) {
    bq[2 * r]     = (_Float16)(K0[r] * scale);
    bq[2 * r + 1] = (_Float16)(K1[r] * scale);
  }

  asm volatile("" ::: "memory");   // Ytp writes ordered before phase-D reads

  // ---- Phase D: dK partial = K' @ Y over own 32-j window ----
  f32x4 c0 = {0,0,0,0}, c1 = {0,0,0,0}, c2 = {0,0,0,0}, c3 = {0,0,0,0};
  f32x4 c4 = {0,0,0,0}, c5 = {0,0,0,0}, c6 = {0,0,0,0}, c7 = {0,0,0,0};
  #pragma unroll
  for (int dt = 0; dt < 8; ++dt) {
    int d = dt * 16 + li;
    f16x8 af = *(const f16x8*)((const char*)ytp + d * 64 + g * 16);
    f32x4& cc = dt == 0 ? c0 : dt == 1 ? c1 : dt == 2 ? c2 : dt == 3 ? c3
              : dt == 4 ? c4 : dt == 5 ? c5 : dt == 6 ? c6 : c7;
    cc = __builtin_amdgcn_mfma_f32_16x16x32_f16(af, bq, cc, 0, 0, 0);
  }

  asm volatile("" ::: "memory");   // phase-D reads ordered before dkpart writes

  // unscale + write wave-partial [i=li][d] (aliases Ytp; same-wave DS in order)
  #pragma unroll
  for (int dt = 0; dt < 8; ++dt) {
    f32x4 cc = dt == 0 ? c0 : dt == 1 ? c1 : dt == 2 ? c2 : dt == 3 ? c3
             : dt == 4 ? c4 : dt == 5 ? c5 : dt == 6 ? c6 : c7;
    f32x4 v = { cc.x * invs, cc.y * invs, cc.z * invs, cc.w * invs };
    *(f32x4*)((char*)dkw + li * 512 + dt * 64 + g * 16) = v;
  }
  __syncthreads();   // the ONE barrier: all wave-partials visible

  // ---- cross-wave sum -> slab (coalesced full-line stores) ----
  {
    int i = tid >> 4, s = tid & 15;
    int off = i * 128 + s * 8;
    f32x4 r0 = {0,0,0,0}, r1 = {0,0,0,0};
    #pragma unroll
    for (int w2 = 0; w2 < 4; ++w2) {
      const float* p = (const float*)smem[w2];
      f32x4 a = *(const f32x4*)(p + off);
      f32x4 b = *(const f32x4*)(p + off + 4);
      r0.x += a.x; r0.y += a.y; r0.z += a.z; r0.w += a.w;
      r1.x += b.x; r1.y += b.y; r1.z += b.z; r1.w += b.w;
    }
    float* pb = ws + WS_S + (size_t)js * (NN * DD) + (size_t)(ib * 16 + i) * DD + s * 8;
    *(f32x4*)pb = r0;
    *(f32x4*)(pb + 4) = r1;
  }
}

// dK[i][d] = inv_h2 * (sum_js part[js][i][d] - (sum_{js,w} S[js*4+w][i]) * X[i][d])
__global__ __launch_bounds__(128) void dk_reduce(const float* __restrict__ X,
                                                 const int* __restrict__ hp,
                                                 const float* __restrict__ ws,
                                                 float* __restrict__ out) {
  const int unit = blockIdx.x * 128 + threadIdx.x;   // 0..32767 (f32x4 units)
  const int i  = unit >> 5;
  const int d0 = (unit & 31) * 4;
  const float fh = (float)hp[0];
  const float inv_h2 = 1.0f / (fh * fh);

  f32x4 acc = {0.f, 0.f, 0.f, 0.f};
  float s = 0.f;
  #pragma unroll
  for (int q = 0; q < 32; ++q) s += ws[(size_t)q * NN + i];
  #pragma unroll
  for (int js = 0; js < 8; ++js) {
    f32x4 p = *(const f32x4*)(ws + WS_S + (size_t)js * (NN * DD) + (size_t)i * DD + d0);
    acc.x += p.x; acc.y += p.y; acc.z += p.z; acc.w += p.w;
  }
  f32x4 xv = *(const f32x4*)(X + (size_t)i * DD + d0);
  f32x4 r;
  r.x = (acc.x - s * xv.x) * inv_h2;
  r.y = (acc.y - s * xv.y) * inv_h2;
  r.z = (acc.z - s * xv.z) * inv_h2;
  r.w = (acc.w - s * xv.w) * inv_h2;
  *(f32x4*)(out + (size_t)NN * NN + (size_t)i * DD + d0) = r;
}

extern "C" void kernel_launch(void* const* d_in, const int* in_sizes, int n_in,
                              void* d_out, int out_size, void* d_ws, size_t ws_size,
                              hipStream_t stream) {
  const float* X  = (const float*)d_in[0];
  const float* Y  = (const float*)d_in[1];
  const int*   hp = (const int*)d_in[2];
  float* out = (float*)d_out;
  float* ws  = (float*)d_ws;    // needs (32768 + 1048576) f32 ≈ 4.3 MB

  hipLaunchKernelGGL(gk_main, dim3(8, 64), dim3(256), 0, stream, X, Y, hp, out, ws);
  hipLaunchKernelGGL(dk_reduce, dim3(256), dim3(128), 0, stream, X, hp, ws, out);
}